// Round 1
// baseline (459.606 us; speedup 1.0000x reference)
//
#include <hip/hip_runtime.h>
#include <hip/hip_bf16.h>
#include <math.h>

#define AS1 __attribute__((address_space(1)))
#define AS3 __attribute__((address_space(3)))

typedef __bf16 bf16x8 __attribute__((ext_vector_type(8)));
typedef __bf16 bf16x4 __attribute__((ext_vector_type(4)));
typedef float  f32x4  __attribute__((ext_vector_type(4)));

static constexpr int   N_ROWS   = 10000;
static constexpr int   T_TILES  = 79;            // ceil(10000/128)
static constexpr int   NP       = T_TILES * 128; // 10112 padded rows
static constexpr int   D        = 256;           // K for all GEMMs
static constexpr float INV_TAU  = 2.0f;          // 1/0.5
static constexpr float PAD_COLS = 112.0f;        // NP - N_ROWS, exp(0)=1 each
static constexpr int   F_TILES  = T_TILES * T_TILES;          // 6241
static constexpr int   Y_TILES  = T_TILES * (T_TILES + 1) / 2; // 3160

// ---------------------------------------------------------------------------
// Core 128x128 tile GEMM, K=256 (4 stages of BK=64), bf16 MFMA 16x16x32.
// A,B both row-major [rows][256] (NT layout: C = A @ B^T).
// LDS tiles [128][64] bf16 with XOR chunk swizzle (T2): physical 16B chunk
// = logical chunk ^ (row&7). Staged with global_load_lds (linear dest) by
// pre-swizzling the *global* source chunk; reads apply the same XOR.
// Wave grid 2x2, each wave = 64x64 = 4x4 frags of 16x16.
// ---------------------------------------------------------------------------
__device__ __forceinline__ void tile_gemm_128(
    const __bf16* __restrict__ Abase, const __bf16* __restrict__ Bbase,
    char* ldsA, char* ldsB, int tid, f32x4 acc[4][4])
{
  const int l      = tid & 63;
  const int wr     = (tid >> 7) & 1;
  const int wc     = (tid >> 6) & 1;
  const int srow   = tid >> 3;   // 0..31 (staging row within round)
  const int schunk = tid & 7;    // staging 16B chunk
  const int lrow   = l & 15;
  const int lk     = l >> 4;

  for (int kt = 0; kt < 4; ++kt) {
    __syncthreads();                       // previous-iter reads done
    const int kbase = kt * 64;
#pragma unroll
    for (int rr = 0; rr < 4; ++rr) {
      const int row = rr * 32 + srow;
      const int lc  = schunk ^ (row & 7);  // inverse-swizzled source chunk
      const __bf16* ga = Abase + (size_t)row * D + kbase + lc * 8;
      const __bf16* gb = Bbase + (size_t)row * D + kbase + lc * 8;
      __builtin_amdgcn_global_load_lds((const AS1 void*)ga,
          (AS3 void*)(ldsA + rr * 4096 + tid * 16), 16, 0, 0);
      __builtin_amdgcn_global_load_lds((const AS1 void*)gb,
          (AS3 void*)(ldsB + rr * 4096 + tid * 16), 16, 0, 0);
    }
    __syncthreads();                       // compiler drains vmcnt here
#pragma unroll
    for (int ks = 0; ks < 2; ++ks) {
      bf16x8 af[4], bfr[4];
#pragma unroll
      for (int m = 0; m < 4; ++m) {
        const int row = wr * 64 + m * 16 + lrow;
        const int off = row * 128 + ((ks * 64 + lk * 16) ^ ((row & 7) << 4));
        af[m] = *(const bf16x8*)(ldsA + off);
      }
#pragma unroll
      for (int n = 0; n < 4; ++n) {
        const int row = wc * 64 + n * 16 + lrow;
        const int off = row * 128 + ((ks * 64 + lk * 16) ^ ((row & 7) << 4));
        bfr[n] = *(const bf16x8*)(ldsB + off);
      }
#pragma unroll
      for (int m = 0; m < 4; ++m)
#pragma unroll
        for (int n = 0; n < 4; ++n)
          acc[m][n] = __builtin_amdgcn_mfma_f32_16x16x32_bf16(
              af[m], bfr[n], acc[m][n], 0, 0, 0);
    }
  }
}

// ---------------------------------------------------------------------------
// Gram kernel: all 5 distinct similarity matrices, exp + row/col sums.
// S layout [6][NP]: S11,S12,S13,S21,S22,S23 (float, atomically accumulated).
// ---------------------------------------------------------------------------
__global__ __launch_bounds__(256, 2) void gram_kernel(
    const __bf16* __restrict__ p1, const __bf16* __restrict__ p2,
    const __bf16* __restrict__ p3, float* __restrict__ S)
{
  int bid = blockIdx.x;
  const __bf16 *P, *Q;
  float *Srow, *Scol;
  int r, c;
  if (bid < 3 * F_TILES) {
    const int job = bid / F_TILES, t = bid % F_TILES;
    r = t / T_TILES; c = t % T_TILES;
    if (job == 0)      { P = p1; Q = p2; Srow = S + 1 * NP; Scol = S + 3 * NP; }
    else if (job == 1) { P = p1; Q = p3; Srow = S + 2 * NP; Scol = nullptr; }
    else               { P = p2; Q = p3; Srow = S + 5 * NP; Scol = nullptr; }
  } else {
    const int s = bid - 3 * F_TILES;
    const int job = s / Y_TILES;
    int rem = s % Y_TILES, rr = 0, w = T_TILES;
    while (rem >= w) { rem -= w; ++rr; --w; }
    r = rr; c = rr + rem;                      // c >= r (upper triangle)
    const __bf16* pp = job ? p2 : p1;
    float* SS = job ? (S + 4 * NP) : (S + 0 * NP);
    P = pp; Q = pp; Srow = SS; Scol = (c > r) ? SS : nullptr;
  }

  __shared__ __align__(16) char lds[32768];
  f32x4 acc[4][4];
#pragma unroll
  for (int m = 0; m < 4; ++m)
#pragma unroll
    for (int n = 0; n < 4; ++n)
#pragma unroll
      for (int q = 0; q < 4; ++q) acc[m][n][q] = 0.f;

  tile_gemm_128(P + (size_t)r * 128 * D, Q + (size_t)c * 128 * D,
                lds, lds + 16384, threadIdx.x, acc);

  const int tid = threadIdx.x, l = tid & 63;
  const int wr = (tid >> 7) & 1, wc = (tid >> 6) & 1;

  // exp(sim / tau), in place (padded rows/cols are exact zeros -> exp=1,
  // corrected by -PAD_COLS in the loss kernel)
#pragma unroll
  for (int m = 0; m < 4; ++m)
#pragma unroll
    for (int n = 0; n < 4; ++n)
#pragma unroll
      for (int q = 0; q < 4; ++q)
        acc[m][n][q] = __expf(acc[m][n][q] * INV_TAU);

  // row sums: reduce over 16 lanes (same l>>4 group) covering the 64 cols
#pragma unroll
  for (int m = 0; m < 4; ++m) {
    f32x4 v;
#pragma unroll
    for (int q = 0; q < 4; ++q)
      v[q] = acc[m][0][q] + acc[m][1][q] + acc[m][2][q] + acc[m][3][q];
#pragma unroll
    for (int mask = 1; mask < 16; mask <<= 1)
#pragma unroll
      for (int q = 0; q < 4; ++q) v[q] += __shfl_xor(v[q], mask, 64);
    if ((l & 15) == 0) {
      const int grow = r * 128 + wr * 64 + m * 16 + (l >> 4) * 4;
#pragma unroll
      for (int q = 0; q < 4; ++q) atomicAdd(&Srow[grow + q], v[q]);
    }
  }

  // col sums (transpose accumulation) when needed
  if (Scol) {
#pragma unroll
    for (int n = 0; n < 4; ++n) {
      float sc = 0.f;
#pragma unroll
      for (int m = 0; m < 4; ++m)
#pragma unroll
        for (int q = 0; q < 4; ++q) sc += acc[m][n][q];
      sc += __shfl_xor(sc, 16, 64);
      sc += __shfl_xor(sc, 32, 64);
      if (l < 16) atomicAdd(&Scol[c * 128 + wc * 64 + n * 16 + l], sc);
    }
  }
}

// ---------------------------------------------------------------------------
// Projection GEMM: C = A @ B^T + bias, MODE 0: elu -> bf16, MODE 1: f32.
// ---------------------------------------------------------------------------
template <int MODE>
__global__ __launch_bounds__(256, 2) void proj_kernel(
    const __bf16* __restrict__ A, const __bf16* __restrict__ B,
    const float* __restrict__ bias, void* __restrict__ out)
{
  const int r = blockIdx.x, c = blockIdx.y;
  __shared__ __align__(16) char lds[32768];
  f32x4 acc[4][4];
#pragma unroll
  for (int m = 0; m < 4; ++m)
#pragma unroll
    for (int n = 0; n < 4; ++n)
#pragma unroll
      for (int q = 0; q < 4; ++q) acc[m][n][q] = 0.f;

  tile_gemm_128(A + (size_t)r * 128 * D, B + (size_t)c * 128 * D,
                lds, lds + 16384, threadIdx.x, acc);

  const int tid = threadIdx.x, l = tid & 63;
  const int wr = (tid >> 7) & 1, wc = (tid >> 6) & 1;
#pragma unroll
  for (int n = 0; n < 4; ++n) {
    const int gcol = c * 128 + wc * 64 + n * 16 + (l & 15);
    const float bn = bias[gcol];
#pragma unroll
    for (int m = 0; m < 4; ++m) {
#pragma unroll
      for (int q = 0; q < 4; ++q) {
        const int grow = r * 128 + wr * 64 + m * 16 + (l >> 4) * 4 + q;
        float v = acc[m][n][q] + bn;
        if (MODE == 0) {
          float o = v > 0.f ? v : (__expf(v) - 1.f);   // ELU
          ((__bf16*)out)[(size_t)grow * D + gcol] = (__bf16)o;
        } else {
          ((float*)out)[(size_t)grow * D + gcol] = v;
        }
      }
    }
  }
}

// ---------------------------------------------------------------------------
__global__ void cast_kernel(const float* __restrict__ src,
                            __bf16* __restrict__ dst, int n)
{
  int idx = (blockIdx.x * blockDim.x + threadIdx.x) * 4;
  const int stride = gridDim.x * blockDim.x * 4;
  for (; idx < n; idx += stride) {
    const float4 v = *(const float4*)(src + idx);
    bf16x4 o;
    o[0] = (__bf16)v.x; o[1] = (__bf16)v.y;
    o[2] = (__bf16)v.z; o[3] = (__bf16)v.w;
    *(bf16x4*)(dst + idx) = o;
  }
}

// one wave per row: L2-normalize; padded rows written as exact zeros
__global__ void norm_kernel(const float* __restrict__ praw,
                            __bf16* __restrict__ p)
{
  const int row = blockIdx.x * 4 + (threadIdx.x >> 6);
  const int l = threadIdx.x & 63;
  const size_t base = (size_t)row * D + l * 4;
  if (row < N_ROWS) {
    const float4 v = *(const float4*)(praw + base);
    float ss = v.x * v.x + v.y * v.y + v.z * v.z + v.w * v.w;
#pragma unroll
    for (int mask = 1; mask < 64; mask <<= 1) ss += __shfl_xor(ss, mask, 64);
    const float inv = 1.0f / fmaxf(sqrtf(ss), 1e-12f);
    bf16x4 o;
    o[0] = (__bf16)(v.x * inv); o[1] = (__bf16)(v.y * inv);
    o[2] = (__bf16)(v.z * inv); o[3] = (__bf16)(v.w * inv);
    *(bf16x4*)(p + base) = o;
  } else {
    bf16x4 o;
    o[0] = o[1] = o[2] = o[3] = (__bf16)0.0f;
    *(bf16x4*)(p + base) = o;
  }
}

// per-row diagonal terms: dg [5][NP] = exp(d11,d22,d12,d13,d23 / tau)
__global__ void diag_kernel(const __bf16* __restrict__ p1,
                            const __bf16* __restrict__ p2,
                            const __bf16* __restrict__ p3,
                            float* __restrict__ dg)
{
  const int row = blockIdx.x * 4 + (threadIdx.x >> 6);
  const int l = threadIdx.x & 63;
  if (row >= N_ROWS) return;
  const size_t base = (size_t)row * D + l * 4;
  const bf16x4 a = *(const bf16x4*)(p1 + base);
  const bf16x4 b = *(const bf16x4*)(p2 + base);
  const bf16x4 e = *(const bf16x4*)(p3 + base);
  float d11 = 0, d22 = 0, d12 = 0, d13 = 0, d23 = 0;
#pragma unroll
  for (int q = 0; q < 4; ++q) {
    const float fa = (float)a[q], fb = (float)b[q], fe = (float)e[q];
    d11 += fa * fa; d22 += fb * fb; d12 += fa * fb;
    d13 += fa * fe; d23 += fb * fe;
  }
#pragma unroll
  for (int mask = 1; mask < 64; mask <<= 1) {
    d11 += __shfl_xor(d11, mask, 64);
    d22 += __shfl_xor(d22, mask, 64);
    d12 += __shfl_xor(d12, mask, 64);
    d13 += __shfl_xor(d13, mask, 64);
    d23 += __shfl_xor(d23, mask, 64);
  }
  if (l == 0) {
    dg[0 * NP + row] = __expf(d11 * INV_TAU);
    dg[1 * NP + row] = __expf(d22 * INV_TAU);
    dg[2 * NP + row] = __expf(d12 * INV_TAU);
    dg[3 * NP + row] = __expf(d13 * INV_TAU);
    dg[4 * NP + row] = __expf(d23 * INV_TAU);
  }
}

__global__ void loss_kernel(const float* __restrict__ S,
                            const float* __restrict__ dg,
                            float* __restrict__ out)
{
  float local = 0.f;
  for (int i = blockIdx.x * blockDim.x + threadIdx.x; i < N_ROWS;
       i += gridDim.x * blockDim.x) {
    const float s11 = S[0 * NP + i] - PAD_COLS;
    const float s12 = S[1 * NP + i] - PAD_COLS;
    const float s13 = S[2 * NP + i] - PAD_COLS;
    const float s21 = S[3 * NP + i] - PAD_COLS;
    const float s22 = S[4 * NP + i] - PAD_COLS;
    const float s23 = S[5 * NP + i] - PAD_COLS;
    const float d11 = dg[0 * NP + i], d22 = dg[1 * NP + i];
    const float d12 = dg[2 * NP + i], d13 = dg[3 * NP + i];
    const float d23 = dg[4 * NP + i];
    const float den1 = s11 + s12 + s13 - d11 - d12 - d13;
    const float den2 = s22 + s21 + s23 - d22 - d12 - d23;
    local += 0.5f * (__logf(den1) + __logf(den2)) - __logf(d12);
  }
#pragma unroll
  for (int mask = 1; mask < 64; mask <<= 1) local += __shfl_xor(local, mask, 64);
  __shared__ float wsum[4];
  if ((threadIdx.x & 63) == 0) wsum[threadIdx.x >> 6] = local;
  __syncthreads();
  if (threadIdx.x == 0) {
    const float t = wsum[0] + wsum[1] + wsum[2] + wsum[3];
    atomicAdd(out, t * (1.0f / (float)N_ROWS));
  }
}

// ---------------------------------------------------------------------------
extern "C" void kernel_launch(void* const* d_in, const int* in_sizes, int n_in,
                              void* d_out, int out_size, void* d_ws,
                              size_t ws_size, hipStream_t stream)
{
  const float* z[3] = {(const float*)d_in[0], (const float*)d_in[1],
                       (const float*)d_in[2]};
  const float* W1 = (const float*)d_in[3];
  const float* b1 = (const float*)d_in[4];
  const float* W2 = (const float*)d_in[5];
  const float* b2 = (const float*)d_in[6];

  char* ws = (char*)d_ws;
  size_t off = 0;
  auto alloc = [&](size_t bytes) -> char* {
    char* p = ws + off;
    off += (bytes + 511) & ~(size_t)511;
    return p;
  };
  __bf16* pB[3];
  for (int m = 0; m < 3; ++m) pB[m] = (__bf16*)alloc((size_t)NP * D * 2);
  __bf16* w1b  = (__bf16*)alloc((size_t)D * D * 2);
  __bf16* w2b  = (__bf16*)alloc((size_t)D * D * 2);
  __bf16* zb   = (__bf16*)alloc((size_t)NP * D * 2);
  __bf16* hB   = (__bf16*)alloc((size_t)NP * D * 2);
  float*  praw = (float*) alloc((size_t)NP * D * 4);
  float*  Sv   = (float*) alloc((size_t)6 * NP * 4);
  float*  dg   = (float*) alloc((size_t)5 * NP * 4);

  hipMemsetAsync(Sv, 0, (size_t)6 * NP * 4, stream);
  hipMemsetAsync(d_out, 0, sizeof(float), stream);

  cast_kernel<<<64, 256, 0, stream>>>(W1, w1b, D * D);
  cast_kernel<<<64, 256, 0, stream>>>(W2, w2b, D * D);

  for (int m = 0; m < 3; ++m) {
    cast_kernel<<<2500, 256, 0, stream>>>(z[m], zb, N_ROWS * D);
    dim3 g(T_TILES, 2);
    proj_kernel<0><<<g, 256, 0, stream>>>(zb, w1b, b1, (void*)hB);
    proj_kernel<1><<<g, 256, 0, stream>>>(hB, w2b, b2, (void*)praw);
    norm_kernel<<<NP / 4, 256, 0, stream>>>(praw, pB[m]);
  }

  gram_kernel<<<3 * F_TILES + 2 * Y_TILES, 256, 0, stream>>>(
      pB[0], pB[1], pB[2], Sv);
  diag_kernel<<<2500, 256, 0, stream>>>(pB[0], pB[1], pB[2], dg);
  loss_kernel<<<64, 256, 0, stream>>>(Sv, dg, (float*)d_out);
}